// Round 1
// baseline (118.621 us; speedup 1.0000x reference)
//
#include <hip/hip_runtime.h>
#include <hip/hip_bf16.h>
#include <math.h>

#define BB 8
#define CC 128
#define NPTS 8192
#define KNBR 16

__device__ __forceinline__ unsigned short f2bf(float f) {
    unsigned int u = __float_as_uint(f);
    unsigned int r = (u + 0x7fffu + ((u >> 16) & 1u)) >> 16;
    return (unsigned short)r;
}
__device__ __forceinline__ float bf2f(unsigned short h) {
    return __uint_as_float(((unsigned int)h) << 16);
}
__device__ __forceinline__ float lrelu(float v) { return v >= 0.0f ? v : 0.2f * v; }

// ---------------- Kernel 1: hypernetwork -> W^T (bf16) + reg loss ----------------
__global__ void hyper_kernel(const float* __restrict__ fc11_w, const float* __restrict__ fc11_b,
                             const float* __restrict__ fc12_w, const float* __restrict__ fc12_b,
                             const float* __restrict__ fcsk_w, const float* __restrict__ fcsk_b,
                             const int* __restrict__ up, unsigned short* __restrict__ Wt,
                             float* __restrict__ reg_out) {
    __shared__ float h[32];
    __shared__ float red[256];
    int t = threadIdx.x;
    // s = sqrt(ups[idx])/sqrt(ups[-1]) replicated in f64 exactly like numpy
    double us = (double)(*up);
    int idxq = (int)((us * us - 1.1) / 0.1);
    float s = (float)(sqrt(1.1 + 0.1 * (double)idxq) / sqrt(1.1 + 0.1 * 79.0));
    if (t < 32) {
        float v = fc11_w[t] * s + fc11_b[t];
        h[t] = lrelu(v);
    }
    __syncthreads();
    int j = blockIdx.x * 256 + t;  // 0..16383
    const float* wr = fc12_w + j * 32;
    float acc = fc12_b[j] + fcsk_w[j] * s + fcsk_b[j];
#pragma unroll
    for (int k = 0; k < 32; ++k) acc = fmaf(wr[k], h[k], acc);
    int o = j >> 7, i = j & 127;
    Wt[i * 128 + o] = f2bf(acc);  // store transposed: Wt[i][o] = W[o][i]
    red[t] = acc * acc;
    __syncthreads();
    for (int st = 128; st > 0; st >>= 1) {
        if (t < st) red[t] += red[t + st];
        __syncthreads();
    }
    if (t == 0) atomicAdd(reg_out, 0.5f * red[0]);
}

// ---------------- Kernel 2: out = W1@x/17 + x ; y2t = (W2@x)^T in bf16 ----------------
// grid: BB * (NPTS/64) * 2 halves.  block 256.
__global__ __launch_bounds__(256) void matmul_kernel(const float* __restrict__ points,
                                                     const unsigned short* __restrict__ W1t,
                                                     const unsigned short* __restrict__ W2t,
                                                     float* __restrict__ out,
                                                     unsigned short* __restrict__ y2t) {
    __shared__ float xs[128][68];            // lrelu(x) tile, f32, padded
    __shared__ unsigned short W1s[128][64];  // W1^T half (o-range), bf16
    __shared__ unsigned short W2s[128][64];

    int bid = blockIdx.x;
    int h = bid & 1;
    int ntile = (bid >> 1) & (NPTS / 64 - 1);
    int b = bid >> 8;
    int n0 = ntile * 64;
    int t = threadIdx.x;

    // stage x tile (coalesced float4 rows), apply lrelu
#pragma unroll
    for (int iter = 0; iter < 8; ++iter) {
        int row = iter * 16 + (t >> 4);
        int col = (t & 15) * 4;
        float4 v = *(const float4*)(points + ((size_t)(b * CC + row)) * NPTS + n0 + col);
        v.x = lrelu(v.x); v.y = lrelu(v.y); v.z = lrelu(v.z); v.w = lrelu(v.w);
        *(float4*)&xs[row][col] = v;
    }
    // stage W halves (bf16, 16 KB each)
#pragma unroll
    for (int iter = 0; iter < 4; ++iter) {
        int chunk = iter * 256 + t;  // 1024 chunks of 8 bf16
        int row = chunk >> 3;
        int c8 = (chunk & 7) * 8;
        *(uint4*)&W1s[row][c8] = *(const uint4*)(W1t + row * 128 + h * 64 + c8);
        *(uint4*)&W2s[row][c8] = *(const uint4*)(W2t + row * 128 + h * 64 + c8);
    }
    __syncthreads();

    int og = t & 15;   // 16 o-groups * 4 = 64 outputs (this half)
    int ng = t >> 4;   // 16 n-groups * 4 = 64 columns
    float acc1[4][4], acc2[4][4];
#pragma unroll
    for (int a = 0; a < 4; ++a)
#pragma unroll
        for (int j = 0; j < 4; ++j) { acc1[a][j] = 0.0f; acc2[a][j] = 0.0f; }

#pragma unroll 4
    for (int i = 0; i < 128; ++i) {
        float4 xv = *(const float4*)&xs[i][ng * 4];
        ushort4 u1 = *(const ushort4*)&W1s[i][og * 4];
        ushort4 u2 = *(const ushort4*)&W2s[i][og * 4];
        float xvf[4] = {xv.x, xv.y, xv.z, xv.w};
        float w1f[4] = {bf2f(u1.x), bf2f(u1.y), bf2f(u1.z), bf2f(u1.w)};
        float w2f[4] = {bf2f(u2.x), bf2f(u2.y), bf2f(u2.z), bf2f(u2.w)};
#pragma unroll
        for (int a = 0; a < 4; ++a)
#pragma unroll
            for (int j = 0; j < 4; ++j) {
                acc1[a][j] = fmaf(w1f[a], xvf[j], acc1[a][j]);
                acc2[a][j] = fmaf(w2f[a], xvf[j], acc2[a][j]);
            }
    }

    const float inv17 = 1.0f / 17.0f;
    // center-conv partial + residual -> d_out ([B][C][N] layout, coalesced float4)
#pragma unroll
    for (int a = 0; a < 4; ++a) {
        int o = h * 64 + og * 4 + a;
        float4 r;
        r.x = fmaf(acc1[a][0], inv17, xs[o][ng * 4 + 0]);
        r.y = fmaf(acc1[a][1], inv17, xs[o][ng * 4 + 1]);
        r.z = fmaf(acc1[a][2], inv17, xs[o][ng * 4 + 2]);
        r.w = fmaf(acc1[a][3], inv17, xs[o][ng * 4 + 3]);
        *(float4*)(out + ((size_t)(b * CC + o)) * NPTS + n0 + ng * 4) = r;
    }
    // y2 transposed ([B][N][C] bf16) for the gather kernel
#pragma unroll
    for (int j = 0; j < 4; ++j) {
        int n = n0 + ng * 4 + j;
        ushort4 w;
        w.x = f2bf(acc2[0][j]); w.y = f2bf(acc2[1][j]);
        w.z = f2bf(acc2[2][j]); w.w = f2bf(acc2[3][j]);
        *(ushort4*)(y2t + ((size_t)(b * NPTS + n)) * CC + h * 64 + og * 4) = w;
    }
}

// ---------------- Kernel 3: out += (sum_k y2t[idx]) / 17 ----------------
// grid: BB * (NPTS/64). block 256 (4 waves; wave w sums 16 n's; lane owns c-pair)
__global__ __launch_bounds__(256) void gather_kernel(const unsigned short* __restrict__ y2t,
                                                     const int* __restrict__ indices,
                                                     float* __restrict__ out) {
    __shared__ int idx_s[64][16];
    __shared__ float g[64][134];  // pad 134: conflict-light both phases
    int t = threadIdx.x;
    int bid = blockIdx.x;
    int b = bid >> 7;
    int n0 = (bid & 127) * 64;

#pragma unroll
    for (int iter = 0; iter < 4; ++iter) {
        int chunk = iter * 256 + t;  // 1024 ints, fully coalesced
        idx_s[chunk >> 4][chunk & 15] = indices[((size_t)(b * NPTS + n0)) * KNBR + chunk];
    }
    __syncthreads();

    int w = t >> 6, l = t & 63;
    const unsigned short* ybase = y2t + (size_t)b * NPTS * CC + 2 * l;
    for (int nn = w * 16; nn < w * 16 + 16; ++nn) {
        float s0 = 0.0f, s1 = 0.0f;
#pragma unroll
        for (int k = 0; k < KNBR; ++k) {
            int j = idx_s[nn][k];
            unsigned int u = *(const unsigned int*)(ybase + (size_t)j * CC);
            s0 += bf2f((unsigned short)(u & 0xffffu));
            s1 += bf2f((unsigned short)(u >> 16));
        }
        g[nn][2 * l] = s0;
        g[nn][2 * l + 1] = s1;
    }
    __syncthreads();

    const float inv17 = 1.0f / 17.0f;
#pragma unroll 4
    for (int iter = 0; iter < 32; ++iter) {
        int c = iter * 4 + w;
        float* p = out + ((size_t)(b * CC + c)) * NPTS + n0 + l;
        *p += g[l][c] * inv17;  // coalesced RMW along n
    }
}

extern "C" void kernel_launch(void* const* d_in, const int* in_sizes, int n_in,
                              void* d_out, int out_size, void* d_ws, size_t ws_size,
                              hipStream_t stream) {
    const float* points = (const float*)d_in[0];
    const int* indices = (const int*)d_in[1];
    const int* up = (const int*)d_in[2];
    const float* fc11_w1 = (const float*)d_in[3];
    const float* fc11_b1 = (const float*)d_in[4];
    const float* fc12_w1 = (const float*)d_in[5];
    const float* fc12_b1 = (const float*)d_in[6];
    const float* fcsk_w1 = (const float*)d_in[7];
    const float* fcsk_b1 = (const float*)d_in[8];
    const float* fc11_w2 = (const float*)d_in[9];
    const float* fc11_b2 = (const float*)d_in[10];
    const float* fc12_w2 = (const float*)d_in[11];
    const float* fc12_b2 = (const float*)d_in[12];
    const float* fcsk_w2 = (const float*)d_in[13];
    const float* fcsk_b2 = (const float*)d_in[14];

    float* out = (float*)d_out;
    unsigned short* y2t = (unsigned short*)d_ws;                            // 16 MB bf16 [B][N][C]
    unsigned short* W1t = (unsigned short*)((char*)d_ws + (size_t)BB * NPTS * CC * 2);
    unsigned short* W2t = W1t + CC * CC;
    float* reg_out = out + (size_t)BB * CC * NPTS;

    hipMemsetAsync(reg_out, 0, sizeof(float), stream);
    hyper_kernel<<<64, 256, 0, stream>>>(fc11_w1, fc11_b1, fc12_w1, fc12_b1, fcsk_w1, fcsk_b1,
                                         up, W1t, reg_out);
    hyper_kernel<<<64, 256, 0, stream>>>(fc11_w2, fc11_b2, fc12_w2, fc12_b2, fcsk_w2, fcsk_b2,
                                         up, W2t, reg_out);
    matmul_kernel<<<BB * (NPTS / 64) * 2, 256, 0, stream>>>(points, W1t, W2t, out, y2t);
    gather_kernel<<<BB * (NPTS / 64), 256, 0, stream>>>(y2t, indices, out);
}

// Round 2
// 60.130 us; speedup vs baseline: 1.9727x; 1.9727x over previous
//
#include <hip/hip_runtime.h>
#include <hip/hip_bf16.h>
#include <math.h>

#define BB 8
#define CC 128
#define NPTS 8192
#define KNBR 16

typedef __attribute__((ext_vector_type(8))) short bf16x8;
typedef __attribute__((ext_vector_type(4))) float f32x4;

__device__ __forceinline__ unsigned short f2bf(float f) {
    unsigned int u = __float_as_uint(f);
    unsigned int r = (u + 0x7fffu + ((u >> 16) & 1u)) >> 16;
    return (unsigned short)r;
}
__device__ __forceinline__ float bf2f(unsigned short h) {
    return __uint_as_float(((unsigned int)h) << 16);
}
__device__ __forceinline__ float lrelu(float v) { return v >= 0.0f ? v : 0.2f * v; }

// ---------------- Kernel 1: both hypernetworks -> W1,W2 [o][i] bf16 + reg loss ----------------
__global__ void hyper_kernel(const float* __restrict__ fc11_w1, const float* __restrict__ fc11_b1,
                             const float* __restrict__ fc12_w1, const float* __restrict__ fc12_b1,
                             const float* __restrict__ fcsk_w1, const float* __restrict__ fcsk_b1,
                             const float* __restrict__ fc11_w2, const float* __restrict__ fc11_b2,
                             const float* __restrict__ fc12_w2, const float* __restrict__ fc12_b2,
                             const float* __restrict__ fcsk_w2, const float* __restrict__ fcsk_b2,
                             const int* __restrict__ up,
                             unsigned short* __restrict__ W1, unsigned short* __restrict__ W2,
                             float* __restrict__ reg_out) {
    int set = blockIdx.x >> 6;  // 0: W1 params, 1: W2 params
    const float* fc11_w = set ? fc11_w2 : fc11_w1;
    const float* fc11_b = set ? fc11_b2 : fc11_b1;
    const float* fc12_w = set ? fc12_w2 : fc12_w1;
    const float* fc12_b = set ? fc12_b2 : fc12_b1;
    const float* fcsk_w = set ? fcsk_w2 : fcsk_w1;
    const float* fcsk_b = set ? fcsk_b2 : fcsk_b1;
    unsigned short* W = set ? W2 : W1;

    __shared__ float h[32];
    __shared__ float red[256];
    int t = threadIdx.x;
    double us = (double)(*up);
    int idxq = (int)((us * us - 1.1) / 0.1);
    float s = (float)(sqrt(1.1 + 0.1 * (double)idxq) / sqrt(1.1 + 0.1 * 79.0));
    if (t < 32) h[t] = lrelu(fc11_w[t] * s + fc11_b[t]);
    __syncthreads();
    int j = (blockIdx.x & 63) * 256 + t;  // 0..16383 = o*128+i
    const float* wr = fc12_w + j * 32;
    float acc = fc12_b[j] + fcsk_w[j] * s + fcsk_b[j];
#pragma unroll
    for (int k = 0; k < 32; ++k) acc = fmaf(wr[k], h[k], acc);
    W[j] = f2bf(acc);  // natural [o][i] layout
    red[t] = acc * acc;
    __syncthreads();
    for (int st = 128; st > 0; st >>= 1) {
        if (t < st) red[t] += red[t + st];
        __syncthreads();
    }
    if (t == 0) atomicAdd(reg_out, 0.5f * red[0]);
}

// ---------------- Kernel 2 (MFMA): out = W1@x/17 + x ; y2t = (W2@x)^T bf16 ----------------
// grid: BB * NPTS/64 blocks; block 256 = 4 waves; wave w owns o in [32w,32w+32)
__global__ __launch_bounds__(256, 3) void matmul_kernel(const float* __restrict__ points,
                                                        const unsigned short* __restrict__ W1,
                                                        const unsigned short* __restrict__ W2,
                                                        float* __restrict__ out,
                                                        unsigned short* __restrict__ y2t) {
    __shared__ float xf_s[128 * 68];           // lrelu(x) tile f32 [i][n], stride 68
    __shared__ unsigned short xb_s[64 * 136];  // lrelu(x) tile bf16 [n][i], stride 136

    int bid = blockIdx.x;
    int b = bid >> 7;
    int n0 = (bid & 127) * 64;
    int t = threadIdx.x;

    // stage: coalesced float4 reads along n; write f32 [i][n] + transposed bf16 [n][i]
#pragma unroll
    for (int iter = 0; iter < 8; ++iter) {
        int row = iter * 16 + (t >> 4);
        int c4 = (t & 15) * 4;
        float4 v = *(const float4*)(points + ((size_t)(b * CC + row)) * NPTS + n0 + c4);
        v.x = lrelu(v.x); v.y = lrelu(v.y); v.z = lrelu(v.z); v.w = lrelu(v.w);
        *(float4*)(xf_s + row * 68 + c4) = v;
        xb_s[(c4 + 0) * 136 + row] = f2bf(v.x);
        xb_s[(c4 + 1) * 136 + row] = f2bf(v.y);
        xb_s[(c4 + 2) * 136 + row] = f2bf(v.z);
        xb_s[(c4 + 3) * 136 + row] = f2bf(v.w);
    }
    __syncthreads();

    int w = t >> 6, l = t & 63;
    int g = l >> 4, ln = l & 15;
    int o_base = w * 32;

    f32x4 zero = {0.0f, 0.0f, 0.0f, 0.0f};
    f32x4 acc1[2][4], acc2[2][4];
#pragma unroll
    for (int ot = 0; ot < 2; ++ot)
#pragma unroll
        for (int nt = 0; nt < 4; ++nt) { acc1[ot][nt] = zero; acc2[ot][nt] = zero; }

#pragma unroll
    for (int ks = 0; ks < 4; ++ks) {
        int k0 = ks * 32;
        // A-frags (W) direct from global (L2-hot, 32KB each): lane l -> row o, k = k0 + 8g..+7
        bf16x8 wf1[2], wf2[2];
#pragma unroll
        for (int ot = 0; ot < 2; ++ot) {
            int orow = o_base + ot * 16 + ln;
            wf1[ot] = *(const bf16x8*)(W1 + orow * 128 + k0 + 8 * g);
            wf2[ot] = *(const bf16x8*)(W2 + orow * 128 + k0 + 8 * g);
        }
        // B-frags (x) from LDS: lane l -> col n = ln, k = k0 + 8g..+7 (contiguous b128)
        bf16x8 xv[4];
#pragma unroll
        for (int nt = 0; nt < 4; ++nt)
            xv[nt] = *(const bf16x8*)(xb_s + (nt * 16 + ln) * 136 + k0 + 8 * g);
#pragma unroll
        for (int ot = 0; ot < 2; ++ot)
#pragma unroll
            for (int nt = 0; nt < 4; ++nt) {
                acc1[ot][nt] = __builtin_amdgcn_mfma_f32_16x16x32_bf16(wf1[ot], xv[nt], acc1[ot][nt], 0, 0, 0);
                acc2[ot][nt] = __builtin_amdgcn_mfma_f32_16x16x32_bf16(wf2[ot], xv[nt], acc2[ot][nt], 0, 0, 0);
            }
    }

    const float inv17 = 1.0f / 17.0f;
    // D layout: col(n) = ln, row(o) = 4g + reg  [m89]
#pragma unroll
    for (int ot = 0; ot < 2; ++ot)
#pragma unroll
        for (int nt = 0; nt < 4; ++nt) {
            int n_loc = nt * 16 + ln;
            int o_lo = o_base + ot * 16 + 4 * g;
            float* op = out + ((size_t)(b * CC + o_lo)) * NPTS + n0 + n_loc;
#pragma unroll
            for (int r = 0; r < 4; ++r)
                op[(size_t)r * NPTS] = fmaf(acc1[ot][nt][r], inv17, xf_s[(o_lo + r) * 68 + n_loc]);
            ushort4 pk;
            pk.x = f2bf(acc2[ot][nt][0]);
            pk.y = f2bf(acc2[ot][nt][1]);
            pk.z = f2bf(acc2[ot][nt][2]);
            pk.w = f2bf(acc2[ot][nt][3]);
            *(ushort4*)(y2t + ((size_t)(b * NPTS + n0 + n_loc)) * CC + o_lo) = pk;
        }
}

// ---------------- Kernel 3: out += (sum_k y2t[idx]) / 17 ----------------
// XCD-pinned: batch = blockIdx % 8 so each batch's 2MB y2t slice stays in one XCD's L2
__global__ __launch_bounds__(256) void gather_kernel(const unsigned short* __restrict__ y2t,
                                                     const int* __restrict__ indices,
                                                     float* __restrict__ out) {
    __shared__ int idx_s[64][16];
    __shared__ float gbuf[64][134];
    int t = threadIdx.x;
    int bid = blockIdx.x;
    int b = bid & 7;
    int n0 = (bid >> 3) * 64;

#pragma unroll
    for (int iter = 0; iter < 4; ++iter) {
        int chunk = iter * 256 + t;
        idx_s[chunk >> 4][chunk & 15] = indices[((size_t)(b * NPTS + n0)) * KNBR + chunk];
    }
    __syncthreads();

    int w = t >> 6, l = t & 63;
    const unsigned short* ybase = y2t + (size_t)b * NPTS * CC + 2 * l;
    for (int nn = w * 16; nn < w * 16 + 16; ++nn) {
        float s0 = 0.0f, s1 = 0.0f;
#pragma unroll
        for (int k = 0; k < KNBR; ++k) {
            int j = idx_s[nn][k];
            unsigned int u = *(const unsigned int*)(ybase + (size_t)j * CC);
            s0 += bf2f((unsigned short)(u & 0xffffu));
            s1 += bf2f((unsigned short)(u >> 16));
        }
        gbuf[nn][2 * l] = s0;
        gbuf[nn][2 * l + 1] = s1;
    }
    __syncthreads();

    const float inv17 = 1.0f / 17.0f;
#pragma unroll 4
    for (int iter = 0; iter < 32; ++iter) {
        int c = iter * 4 + w;
        float* p = out + ((size_t)(b * CC + c)) * NPTS + n0 + l;
        *p += gbuf[l][c] * inv17;
    }
}

extern "C" void kernel_launch(void* const* d_in, const int* in_sizes, int n_in,
                              void* d_out, int out_size, void* d_ws, size_t ws_size,
                              hipStream_t stream) {
    const float* points = (const float*)d_in[0];
    const int* indices = (const int*)d_in[1];
    const int* up = (const int*)d_in[2];
    const float* fc11_w1 = (const float*)d_in[3];
    const float* fc11_b1 = (const float*)d_in[4];
    const float* fc12_w1 = (const float*)d_in[5];
    const float* fc12_b1 = (const float*)d_in[6];
    const float* fcsk_w1 = (const float*)d_in[7];
    const float* fcsk_b1 = (const float*)d_in[8];
    const float* fc11_w2 = (const float*)d_in[9];
    const float* fc11_b2 = (const float*)d_in[10];
    const float* fc12_w2 = (const float*)d_in[11];
    const float* fc12_b2 = (const float*)d_in[12];
    const float* fcsk_w2 = (const float*)d_in[13];
    const float* fcsk_b2 = (const float*)d_in[14];

    float* out = (float*)d_out;
    unsigned short* y2t = (unsigned short*)d_ws;  // 16 MB bf16 [B][N][C]
    unsigned short* W1 = (unsigned short*)((char*)d_ws + (size_t)BB * NPTS * CC * 2);
    unsigned short* W2 = W1 + CC * CC;
    float* reg_out = out + (size_t)BB * CC * NPTS;

    hipMemsetAsync(reg_out, 0, sizeof(float), stream);
    hyper_kernel<<<128, 256, 0, stream>>>(fc11_w1, fc11_b1, fc12_w1, fc12_b1, fcsk_w1, fcsk_b1,
                                          fc11_w2, fc11_b2, fc12_w2, fc12_b2, fcsk_w2, fcsk_b2,
                                          up, W1, W2, reg_out);
    matmul_kernel<<<BB * (NPTS / 64), 256, 0, stream>>>(points, W1, W2, out, y2t);
    gather_kernel<<<BB * (NPTS / 64), 256, 0, stream>>>(y2t, indices, out);
}

// Round 3
// 54.831 us; speedup vs baseline: 2.1634x; 1.0966x over previous
//
#include <hip/hip_runtime.h>
#include <hip/hip_bf16.h>
#include <math.h>

#define BB 8
#define CC 128
#define NPTS 8192
#define KNBR 16

typedef __attribute__((ext_vector_type(8))) short bf16x8;
typedef __attribute__((ext_vector_type(4))) float f32x4;

__device__ __forceinline__ unsigned short f2bf(float f) {
    unsigned int u = __float_as_uint(f);
    unsigned int r = (u + 0x7fffu + ((u >> 16) & 1u)) >> 16;
    return (unsigned short)r;
}
__device__ __forceinline__ float bf2f(unsigned short h) {
    return __uint_as_float(((unsigned int)h) << 16);
}
__device__ __forceinline__ float lrelu(float v) { return v >= 0.0f ? v : 0.2f * v; }

// ---------------- Kernel 1: both hypernetworks -> W1,W2 [o][i] bf16 + per-block reg partials ----------------
__global__ void hyper_kernel(const float* __restrict__ fc11_w1, const float* __restrict__ fc11_b1,
                             const float* __restrict__ fc12_w1, const float* __restrict__ fc12_b1,
                             const float* __restrict__ fcsk_w1, const float* __restrict__ fcsk_b1,
                             const float* __restrict__ fc11_w2, const float* __restrict__ fc11_b2,
                             const float* __restrict__ fc12_w2, const float* __restrict__ fc12_b2,
                             const float* __restrict__ fcsk_w2, const float* __restrict__ fcsk_b2,
                             const int* __restrict__ up,
                             unsigned short* __restrict__ W1, unsigned short* __restrict__ W2,
                             float* __restrict__ regp) {
    int set = blockIdx.x >> 6;  // 0: W1 params, 1: W2 params
    const float* fc11_w = set ? fc11_w2 : fc11_w1;
    const float* fc11_b = set ? fc11_b2 : fc11_b1;
    const float* fc12_w = set ? fc12_w2 : fc12_w1;
    const float* fc12_b = set ? fc12_b2 : fc12_b1;
    const float* fcsk_w = set ? fcsk_w2 : fcsk_w1;
    const float* fcsk_b = set ? fcsk_b2 : fcsk_b1;
    unsigned short* W = set ? W2 : W1;

    __shared__ float h[32];
    __shared__ float red[256];
    int t = threadIdx.x;
    double us = (double)(*up);
    int idxq = (int)((us * us - 1.1) / 0.1);
    float s = (float)(sqrt(1.1 + 0.1 * (double)idxq) / sqrt(1.1 + 0.1 * 79.0));
    if (t < 32) h[t] = lrelu(fc11_w[t] * s + fc11_b[t]);
    __syncthreads();
    int j = (blockIdx.x & 63) * 256 + t;  // 0..16383 = o*128+i
    const float* wr = fc12_w + j * 32;
    float acc = fc12_b[j] + fcsk_w[j] * s + fcsk_b[j];
#pragma unroll
    for (int k = 0; k < 32; ++k) acc = fmaf(wr[k], h[k], acc);
    W[j] = f2bf(acc);  // natural [o][i] layout
    red[t] = acc * acc;
    __syncthreads();
    for (int st = 128; st > 0; st >>= 1) {
        if (t < st) red[t] += red[t + st];
        __syncthreads();
    }
    if (t == 0) regp[blockIdx.x] = 0.5f * red[0];  // plain store: deterministic, no memset needed
}

// ---------------- Kernel 2 (MFMA): out = W1@x/17 + x ; y2t = (W2@x)^T bf16 ----------------
// grid: BB * NPTS/64 blocks; block 256 = 4 waves; wave w owns o in [32w,32w+32)
__global__ __launch_bounds__(256, 3) void matmul_kernel(const float* __restrict__ points,
                                                        const unsigned short* __restrict__ W1,
                                                        const unsigned short* __restrict__ W2,
                                                        float* __restrict__ out,
                                                        unsigned short* __restrict__ y2t) {
    __shared__ float xf_s[128 * 68];           // lrelu(x) tile f32 [i][n], stride 68
    __shared__ unsigned short xb_s[64 * 136];  // lrelu(x) tile bf16 [n][i], stride 136

    int bid = blockIdx.x;
    int b = bid >> 7;
    int n0 = (bid & 127) * 64;
    int t = threadIdx.x;

    // stage: coalesced float4 reads along n; write f32 [i][n] + transposed bf16 [n][i]
#pragma unroll
    for (int iter = 0; iter < 8; ++iter) {
        int row = iter * 16 + (t >> 4);
        int c4 = (t & 15) * 4;
        float4 v = *(const float4*)(points + ((size_t)(b * CC + row)) * NPTS + n0 + c4);
        v.x = lrelu(v.x); v.y = lrelu(v.y); v.z = lrelu(v.z); v.w = lrelu(v.w);
        *(float4*)(xf_s + row * 68 + c4) = v;
        xb_s[(c4 + 0) * 136 + row] = f2bf(v.x);
        xb_s[(c4 + 1) * 136 + row] = f2bf(v.y);
        xb_s[(c4 + 2) * 136 + row] = f2bf(v.z);
        xb_s[(c4 + 3) * 136 + row] = f2bf(v.w);
    }
    __syncthreads();

    int w = t >> 6, l = t & 63;
    int g = l >> 4, ln = l & 15;
    int o_base = w * 32;

    f32x4 zero = {0.0f, 0.0f, 0.0f, 0.0f};
    f32x4 acc1[2][4], acc2[2][4];
#pragma unroll
    for (int ot = 0; ot < 2; ++ot)
#pragma unroll
        for (int nt = 0; nt < 4; ++nt) { acc1[ot][nt] = zero; acc2[ot][nt] = zero; }

#pragma unroll
    for (int ks = 0; ks < 4; ++ks) {
        int k0 = ks * 32;
        // A-frags (W) direct from global (L2-hot, 32KB each): lane l -> row o, k = k0 + 8g..+7
        bf16x8 wf1[2], wf2[2];
#pragma unroll
        for (int ot = 0; ot < 2; ++ot) {
            int orow = o_base + ot * 16 + ln;
            wf1[ot] = *(const bf16x8*)(W1 + orow * 128 + k0 + 8 * g);
            wf2[ot] = *(const bf16x8*)(W2 + orow * 128 + k0 + 8 * g);
        }
        // B-frags (x) from LDS: lane l -> col n = ln, k = k0 + 8g..+7 (contiguous b128)
        bf16x8 xv[4];
#pragma unroll
        for (int nt = 0; nt < 4; ++nt)
            xv[nt] = *(const bf16x8*)(xb_s + (nt * 16 + ln) * 136 + k0 + 8 * g);
#pragma unroll
        for (int ot = 0; ot < 2; ++ot)
#pragma unroll
            for (int nt = 0; nt < 4; ++nt) {
                acc1[ot][nt] = __builtin_amdgcn_mfma_f32_16x16x32_bf16(wf1[ot], xv[nt], acc1[ot][nt], 0, 0, 0);
                acc2[ot][nt] = __builtin_amdgcn_mfma_f32_16x16x32_bf16(wf2[ot], xv[nt], acc2[ot][nt], 0, 0, 0);
            }
    }

    const float inv17 = 1.0f / 17.0f;
    // D layout: col(n) = ln, row(o) = 4g + reg  [m89]
#pragma unroll
    for (int ot = 0; ot < 2; ++ot)
#pragma unroll
        for (int nt = 0; nt < 4; ++nt) {
            int n_loc = nt * 16 + ln;
            int o_lo = o_base + ot * 16 + 4 * g;
            float* op = out + ((size_t)(b * CC + o_lo)) * NPTS + n0 + n_loc;
#pragma unroll
            for (int r = 0; r < 4; ++r)
                op[(size_t)r * NPTS] = fmaf(acc1[ot][nt][r], inv17, xf_s[(o_lo + r) * 68 + n_loc]);
            ushort4 pk;
            pk.x = f2bf(acc2[ot][nt][0]);
            pk.y = f2bf(acc2[ot][nt][1]);
            pk.z = f2bf(acc2[ot][nt][2]);
            pk.w = f2bf(acc2[ot][nt][3]);
            *(ushort4*)(y2t + ((size_t)(b * NPTS + n0 + n_loc)) * CC + o_lo) = pk;
        }
}

// ---------------- Kernel 3: out += (sum_k y2t[idx]) / 17 ; block 0 also reduces reg partials ----------------
// XCD-pinned: batch = blockIdx % 8 so each batch's 2MB y2t slice stays in one XCD's L2
__global__ __launch_bounds__(256) void gather_kernel(const unsigned short* __restrict__ y2t,
                                                     const int* __restrict__ indices,
                                                     float* __restrict__ out,
                                                     const float* __restrict__ regp,
                                                     float* __restrict__ reg_out) {
    __shared__ int idx_s[64][16];
    __shared__ float gbuf[64][134];
    int t = threadIdx.x;
    int bid = blockIdx.x;
    int b = bid & 7;
    int n0 = (bid >> 3) * 64;

#pragma unroll
    for (int iter = 0; iter < 4; ++iter) {
        int chunk = iter * 256 + t;
        idx_s[chunk >> 4][chunk & 15] = indices[((size_t)(b * NPTS + n0)) * KNBR + chunk];
    }
    __syncthreads();

    int w = t >> 6, l = t & 63;
    const unsigned short* ybase = y2t + (size_t)b * NPTS * CC + 2 * l;
    for (int nn = w * 16; nn < w * 16 + 16; ++nn) {
        float s0 = 0.0f, s1 = 0.0f;
#pragma unroll
        for (int k = 0; k < KNBR; ++k) {
            int j = idx_s[nn][k];
            unsigned int u = *(const unsigned int*)(ybase + (size_t)j * CC);
            s0 += bf2f((unsigned short)(u & 0xffffu));
            s1 += bf2f((unsigned short)(u >> 16));
        }
        gbuf[nn][2 * l] = s0;
        gbuf[nn][2 * l + 1] = s1;
    }
    __syncthreads();

    const float inv17 = 1.0f / 17.0f;
#pragma unroll 4
    for (int iter = 0; iter < 32; ++iter) {
        int c = iter * 4 + w;
        float* p = out + ((size_t)(b * CC + c)) * NPTS + n0 + l;
        *p += gbuf[l][c] * inv17;
    }

    // fold the 128-partial reg-loss reduction into block 0 (one wave, shuffle only)
    if (bid == 0 && t < 64) {
        float v = regp[t] + regp[t + 64];
#pragma unroll
        for (int off = 32; off; off >>= 1) v += __shfl_down(v, off);
        if (t == 0) reg_out[0] = v;
    }
}

extern "C" void kernel_launch(void* const* d_in, const int* in_sizes, int n_in,
                              void* d_out, int out_size, void* d_ws, size_t ws_size,
                              hipStream_t stream) {
    const float* points = (const float*)d_in[0];
    const int* indices = (const int*)d_in[1];
    const int* up = (const int*)d_in[2];
    const float* fc11_w1 = (const float*)d_in[3];
    const float* fc11_b1 = (const float*)d_in[4];
    const float* fc12_w1 = (const float*)d_in[5];
    const float* fc12_b1 = (const float*)d_in[6];
    const float* fcsk_w1 = (const float*)d_in[7];
    const float* fcsk_b1 = (const float*)d_in[8];
    const float* fc11_w2 = (const float*)d_in[9];
    const float* fc11_b2 = (const float*)d_in[10];
    const float* fc12_w2 = (const float*)d_in[11];
    const float* fc12_b2 = (const float*)d_in[12];
    const float* fcsk_w2 = (const float*)d_in[13];
    const float* fcsk_b2 = (const float*)d_in[14];

    float* out = (float*)d_out;
    unsigned short* y2t = (unsigned short*)d_ws;  // 16 MB bf16 [B][N][C]
    unsigned short* W1 = (unsigned short*)((char*)d_ws + (size_t)BB * NPTS * CC * 2);
    unsigned short* W2 = W1 + CC * CC;
    float* regp = (float*)(W2 + CC * CC);  // 128 per-block partials
    float* reg_out = out + (size_t)BB * CC * NPTS;

    hyper_kernel<<<128, 256, 0, stream>>>(fc11_w1, fc11_b1, fc12_w1, fc12_b1, fcsk_w1, fcsk_b1,
                                          fc11_w2, fc11_b2, fc12_w2, fc12_b2, fcsk_w2, fcsk_b2,
                                          up, W1, W2, regp);
    matmul_kernel<<<BB * (NPTS / 64), 256, 0, stream>>>(points, W1, W2, out, y2t);
    gather_kernel<<<BB * (NPTS / 64), 256, 0, stream>>>(y2t, indices, out, regp, reg_out);
}